// Round 1
// baseline (1297.275 us; speedup 1.0000x reference)
//
#include <hip/hip_runtime.h>
#include <math.h>

// Problem constants (reference.py)
#define NROWS  131072
#define PASS   8
#define TRANS  8
#define NB     128
#define HID    256
#define NCOL   (TRANS*NB)   // 1024
#define XCOLS  17           // FLOW_SIZE+1
#define ROWS   32           // rows per block
#define KC     64           // k-chunk staged in LDS

// Fused kernel: per block of 32 rows:
//  phase1: h[32][256] = relu(xA @ W1 + b1) into LDS (stride 257 vs bank conflicts)
//  per transform t (8): GEMM h @ W2[:, t*128 : t*128+128] with W2 chunks staged
//  in LDS, 4r x 4c register micro-tile per thread (rg=tid>>5 covers 4 rows,
//  cg=tid&31 covers 4 cols), then fused epilogue: exp, 32-lane butterfly
//  reduction of {tot, sum_below_bin, e_at_bin}, cdf + jacobian product.
__global__ __launch_bounds__(256, 2)
void gplc_kernel(const float* __restrict__ x,
                 const float* __restrict__ W1,
                 const float* __restrict__ b1,
                 const float* __restrict__ W2,
                 const float* __restrict__ b2,
                 float* __restrict__ out)
{
    __shared__ float xs[ROWS * XCOLS];        // 2176 B
    __shared__ float w1s[PASS * HID];         // 8192 B
    __shared__ float b1s[HID];                // 1024 B
    __shared__ float b2s[NB];                 // 512 B
    __shared__ float hs[ROWS * (HID + 1)];    // 32896 B (pad 257)
    __shared__ float w2s[KC * NB];            // 32768 B
    // total ~77.5 KB -> 2 blocks/CU

    const int tid = threadIdx.x;
    const int r0  = blockIdx.x * ROWS;

    // ---- stage x tile, W1, b1 ----
    for (int i = tid; i < ROWS * XCOLS; i += 256)
        xs[i] = x[(size_t)r0 * XCOLS + i];
    for (int i = tid; i < PASS * HID; i += 256)
        w1s[i] = W1[i];
    if (tid < HID) b1s[tid] = b1[tid];
    __syncthreads();

    // ---- phase 1: h = relu(xA @ W1 + b1); thread = column, loop rows ----
    for (int r = 0; r < ROWS; ++r) {
        float acc = b1s[tid];
        #pragma unroll
        for (int i = 0; i < PASS; ++i)
            acc += xs[r * XCOLS + i] * w1s[i * HID + tid];
        hs[r * (HID + 1) + tid] = fmaxf(acc, 0.f);
    }

    const int rg = tid >> 5;   // 0..7 -> rows rg*4 .. rg*4+3
    const int cg = tid & 31;   // 0..31 -> cols cg*4 .. cg*4+3

    float jf0 = 1.f, jf1 = 1.f, jf2 = 1.f, jf3 = 1.f;

    for (int t = 0; t < TRANS; ++t) {
        float acc[4][4];
        #pragma unroll
        for (int a = 0; a < 4; ++a)
            #pragma unroll
            for (int b = 0; b < 4; ++b) acc[a][b] = 0.f;

        for (int kc = 0; kc < HID / KC; ++kc) {
            __syncthreads();   // protect w2s/b2s from prior readers
            const int k0 = kc * KC;
            // stage W2 chunk [64 x 128] (coalesced float4)
            for (int i = tid * 4; i < KC * NB; i += 1024) {
                const int kk = i >> 7, c = i & 127;
                *(float4*)&w2s[i] =
                    *(const float4*)&W2[(size_t)(k0 + kk) * NCOL + t * NB + c];
            }
            if (kc == 0 && tid < NB) b2s[tid] = b2[t * NB + tid];
            __syncthreads();

            #pragma unroll 4
            for (int k = 0; k < KC; ++k) {
                const int kk = k0 + k;
                const float hv0 = hs[(rg * 4 + 0) * (HID + 1) + kk];
                const float hv1 = hs[(rg * 4 + 1) * (HID + 1) + kk];
                const float hv2 = hs[(rg * 4 + 2) * (HID + 1) + kk];
                const float hv3 = hs[(rg * 4 + 3) * (HID + 1) + kk];
                const float4 wv = *(const float4*)&w2s[k * NB + cg * 4];
                acc[0][0] += hv0 * wv.x; acc[0][1] += hv0 * wv.y;
                acc[0][2] += hv0 * wv.z; acc[0][3] += hv0 * wv.w;
                acc[1][0] += hv1 * wv.x; acc[1][1] += hv1 * wv.y;
                acc[1][2] += hv1 * wv.z; acc[1][3] += hv1 * wv.w;
                acc[2][0] += hv2 * wv.x; acc[2][1] += hv2 * wv.y;
                acc[2][2] += hv2 * wv.z; acc[2][3] += hv2 * wv.w;
                acc[3][0] += hv3 * wv.x; acc[3][1] += hv3 * wv.y;
                acc[3][2] += hv3 * wv.z; acc[3][3] += hv3 * wv.w;
            }
        }

        // ---- fused epilogue for transform t ----
        #pragma unroll
        for (int rr = 0; rr < 4; ++rr) {
            const int r = rg * 4 + rr;
            const float alpha = xs[r * XCOLS + PASS + t] * (float)NB;
            const float fb = floorf(alpha);
            const int  bin = min(max((int)fb, 0), NB - 1);
            const float fr = alpha - fb;   // reference: frac uses unclipped floor

            float tot = 0.f, sb = 0.f, eb = 0.f;
            #pragma unroll
            for (int cc = 0; cc < 4; ++cc) {
                const int col = cg * 4 + cc;
                const float e = __expf(acc[rr][cc] + b2s[col]);
                tot += e;
                sb  += (col < bin)  ? e : 0.f;
                eb  += (col == bin) ? e : 0.f;
            }
            #pragma unroll
            for (int m = 1; m <= 16; m <<= 1) {
                tot += __shfl_xor(tot, m, 64);
                sb  += __shfl_xor(sb,  m, 64);
                eb  += __shfl_xor(eb,  m, 64);
            }
            const float inv = 1.f / tot;
            const float cdf = (eb * fr + sb) * inv;
            const float jfac = eb * (float)NB * inv;
            if (rr == 0) jf0 *= jfac;
            else if (rr == 1) jf1 *= jfac;
            else if (rr == 2) jf2 *= jfac;
            else jf3 *= jfac;
            if (cg == 0)
                out[(size_t)(r0 + r) * XCOLS + PASS + t] = cdf;
        }
    }

    // ---- passthrough xA + jacobian ----
    if (cg == 0) {
        const float jf[4] = {jf0, jf1, jf2, jf3};
        #pragma unroll
        for (int rr = 0; rr < 4; ++rr) {
            const int r = rg * 4 + rr;
            out[(size_t)(r0 + r) * XCOLS + 16] = xs[r * XCOLS + 16] * jf[rr];
        }
    }
    {
        const int r = tid >> 3, c = tid & 7;
        out[(size_t)(r0 + r) * XCOLS + c] = xs[r * XCOLS + c];
    }
}

extern "C" void kernel_launch(void* const* d_in, const int* in_sizes, int n_in,
                              void* d_out, int out_size, void* d_ws, size_t ws_size,
                              hipStream_t stream) {
    (void)in_sizes; (void)n_in; (void)d_ws; (void)ws_size; (void)out_size;
    const float* x  = (const float*)d_in[0];
    const float* W1 = (const float*)d_in[1];
    const float* b1 = (const float*)d_in[2];
    const float* W2 = (const float*)d_in[3];
    const float* b2 = (const float*)d_in[4];
    float* out = (float*)d_out;
    gplc_kernel<<<NROWS / ROWS, 256, 0, stream>>>(x, W1, b1, W2, b2, out);
}

// Round 2
// 268.751 us; speedup vs baseline: 4.8271x; 4.8271x over previous
//
#include <hip/hip_runtime.h>
#include <math.h>

#define NROWS 131072
#define XC    17      // FLOW_SIZE+1
#define ROWS  64      // rows per block
#define HID   256
#define NB    128
#define TRANS 8
#define NCOL  1024
#define HBS   272     // hb row stride in bf16 elems (256+16 pad)

typedef __attribute__((ext_vector_type(8))) short bf16x8;
typedef __attribute__((ext_vector_type(4))) float f32x4;

__device__ __forceinline__ unsigned short f2bf(float f) {
    unsigned int u = __float_as_uint(f);
    return (unsigned short)((u + 0x7FFFu + ((u >> 16) & 1u)) >> 16);  // RNE
}

// W2 [256][1024] fp32 -> w2t [1024 cols][256 k] bf16, k XOR-swizzled within each
// 64-k chunk so LDS B-frag ds_read_b128 is bank-even AND the global->LDS stage
// is a pure linear copy (global_load_lds compatible).
__global__ void prep_w2(const float* __restrict__ W2, unsigned short* __restrict__ w2t) {
    const int g = blockIdx.x * 256 + threadIdx.x;   // g = k*1024 + col
    const int col = g & (NCOL - 1), k = g >> 10;
    w2t[col * HID + (k & ~63) + ((k & 63) ^ ((col & 7) << 3))] = f2bf(W2[g]);
}

__global__ __launch_bounds__(256, 2)
void gplc_mfma(const float* __restrict__ x,
               const float* __restrict__ W1,
               const float* __restrict__ b1,
               const unsigned short* __restrict__ w2t,
               const float* __restrict__ b2,
               float* __restrict__ out)
{
    __shared__ __align__(16) unsigned short hb[ROWS * HBS];      // 34.8 KB
    __shared__ __align__(16) union {
        struct { float w1[8 * HID]; float b1v[HID]; } p;         // phase-1 only
        unsigned short w2[2][128 * 64];                          // 32 KB dbuf
    } u;
    __shared__ float xs[ROWS * XC];                              // 4.3 KB
    __shared__ float red[ROWS][2][4];                            // 2 KB
    // total ~74 KB -> 2 blocks/CU

    const int tid  = threadIdx.x;
    const int lane = tid & 63;
    const int w    = tid >> 6;        // wave 0..3
    const int quad = lane >> 4;
    const int l15  = lane & 15;
    const int r0   = blockIdx.x * ROWS;

    for (int i = tid; i < ROWS * XC; i += 256) xs[i] = x[(size_t)r0 * XC + i];
    for (int i = tid; i < 8 * HID; i += 256)   u.p.w1[i] = W1[i];
    u.p.b1v[tid] = b1[tid];
    __syncthreads();

    // ---- phase 1: h = relu(xA@W1+b1) -> bf16 LDS. thread = col-pair, half rows.
    {
        const int half = tid >> 7;
        const int cp   = tid & 127;
        const float bb0 = u.p.b1v[2 * cp], bb1 = u.p.b1v[2 * cp + 1];
        for (int r = 0; r < 32; ++r) {
            const int row = half * 32 + r;
            float a0 = bb0, a1 = bb1;
            #pragma unroll
            for (int i = 0; i < 8; ++i) {
                const float xv = xs[row * XC + i];
                a0 += xv * u.p.w1[i * HID + 2 * cp];
                a1 += xv * u.p.w1[i * HID + 2 * cp + 1];
            }
            a0 = fmaxf(a0, 0.f); a1 = fmaxf(a1, 0.f);
            *(unsigned int*)&hb[row * HBS + 2 * cp] =
                (unsigned int)f2bf(a0) | ((unsigned int)f2bf(a1) << 16);
        }
    }
    __syncthreads();   // phase-1 done; union region becomes w2 buffers

    const int wr  = (w & 1) * 32;     // wave row base
    const int wc  = (w >> 1) * 64;    // wave col base (within 128)
    const int ksw = (lane & 7) << 3;  // B-frag k swizzle (c&7 == lane&7)

    float jf = 1.f;                   // jacobian product (threads 0..63)

    // stage chunk kc of transform t into buf: 16 KB linear copy, 4 insts/wave
    auto stage = [&](int t, int kc, int buf) {
        #pragma unroll
        for (int j = 0; j < 4; ++j) {
            const int ob = (w * 4 + j) * 512;            // LDS elem base (wave-uniform)
            const int c  = (ob >> 6) + (lane >> 3);      // local col 0..127
            const int kl = (lane & 7) << 3;
            const unsigned short* gp =
                w2t + ((size_t)(t * 128 + c) * HID + kc * 64 + kl);
            unsigned short* lp = &u.w2[buf][ob];
            __builtin_amdgcn_global_load_lds(
                (const __attribute__((address_space(1))) unsigned int*)gp,
                (__attribute__((address_space(3))) unsigned int*)lp, 16, 0, 0);
        }
    };

    for (int t = 0; t < TRANS; ++t) {
        f32x4 acc[2][4];
        #pragma unroll
        for (int a = 0; a < 2; ++a)
            #pragma unroll
            for (int c = 0; c < 4; ++c) acc[a][c] = (f32x4){0.f, 0.f, 0.f, 0.f};

        stage(t, 0, 0);
        #pragma unroll 1
        for (int kc = 0; kc < 4; ++kc) {
            __syncthreads();                       // chunk kc staged; buffers safe
            if (kc < 3) stage(t, kc + 1, (kc + 1) & 1);
            const unsigned short* wsb = u.w2[kc & 1];
            #pragma unroll
            for (int ks = 0; ks < 2; ++ks) {
                const int klog = ks * 32 + quad * 8;
                const bf16x8 a0 = *(const bf16x8*)&hb[(wr + l15) * HBS + kc * 64 + klog];
                const bf16x8 a1 = *(const bf16x8*)&hb[(wr + 16 + l15) * HBS + kc * 64 + klog];
                #pragma unroll
                for (int ct = 0; ct < 4; ++ct) {
                    const int c = wc + ct * 16 + l15;
                    const bf16x8 bf = *(const bf16x8*)&wsb[c * 64 + (klog ^ ksw)];
                    acc[0][ct] = __builtin_amdgcn_mfma_f32_16x16x32_bf16(a0, bf, acc[0][ct], 0, 0, 0);
                    acc[1][ct] = __builtin_amdgcn_mfma_f32_16x16x32_bf16(a1, bf, acc[1][ct], 0, 0, 0);
                }
            }
        }

        // ---- fused epilogue: exp + row-reduce {tot, sum<bin, e@bin} in C-layout
        float bb[4];
        #pragma unroll
        for (int ct = 0; ct < 4; ++ct) bb[ct] = b2[t * NB + wc + ct * 16 + l15];

        #pragma unroll
        for (int rt = 0; rt < 2; ++rt) {
            #pragma unroll
            for (int i = 0; i < 4; ++i) {
                const int row = wr + rt * 16 + quad * 4 + i;
                const float alpha = xs[row * XC + 8 + t] * 128.f;
                const float fb = floorf(alpha);
                const int bin = min(max((int)fb, 0), 127);
                float tot = 0.f, sb = 0.f, eb = 0.f;
                #pragma unroll
                for (int ct = 0; ct < 4; ++ct) {
                    const int col = wc + ct * 16 + l15;
                    const float e = __expf(acc[rt][ct][i] + bb[ct]);
                    tot += e;
                    sb += (col < bin) ? e : 0.f;
                    eb += (col == bin) ? e : 0.f;
                }
                #pragma unroll
                for (int m = 1; m <= 8; m <<= 1) {   // reduce over lane&15
                    tot += __shfl_xor(tot, m);
                    sb  += __shfl_xor(sb, m);
                    eb  += __shfl_xor(eb, m);
                }
                if (l15 == 0) {
                    red[row][w >> 1][0] = tot;
                    red[row][w >> 1][1] = sb;
                    red[row][w >> 1][2] = eb;
                }
            }
        }
        __syncthreads();
        if (tid < 64) {     // combine the two col-half partials, finish cdf
            const float tot = red[tid][0][0] + red[tid][1][0];
            const float sb  = red[tid][0][1] + red[tid][1][1];
            const float eb  = red[tid][0][2] + red[tid][1][2];
            const float alpha = xs[tid * XC + 8 + t] * 128.f;
            const float fb  = floorf(alpha);
            const float inv = 1.f / tot;
            out[(size_t)(r0 + tid) * XC + 8 + t] = (eb * (alpha - fb) + sb) * inv;
            jf *= 128.f * eb * inv;
        }
    }

    if (tid < 64)
        out[(size_t)(r0 + tid) * XC + 16] = xs[tid * XC + 16] * jf;
    for (int i = tid; i < ROWS * 8; i += 256) {
        const int r = i >> 3, c = i & 7;
        out[(size_t)(r0 + r) * XC + c] = xs[r * XC + c];
    }
}

extern "C" void kernel_launch(void* const* d_in, const int* in_sizes, int n_in,
                              void* d_out, int out_size, void* d_ws, size_t ws_size,
                              hipStream_t stream) {
    (void)in_sizes; (void)n_in; (void)ws_size; (void)out_size;
    prep_w2<<<(HID * NCOL) / 256, 256, 0, stream>>>(
        (const float*)d_in[3], (unsigned short*)d_ws);
    gplc_mfma<<<NROWS / ROWS, 256, 0, stream>>>(
        (const float*)d_in[0], (const float*)d_in[1], (const float*)d_in[2],
        (const unsigned short*)d_ws, (const float*)d_in[4], (float*)d_out);
}

// Round 3
// 246.540 us; speedup vs baseline: 5.2619x; 1.0901x over previous
//
#include <hip/hip_runtime.h>
#include <math.h>

#define NROWS 131072
#define XC    17      // FLOW_SIZE+1
#define ROWSB 128     // rows per block
#define HID   256
#define NB    128
#define NCOL  1024
#define LOG2E 1.44269504088896340736f

typedef __attribute__((ext_vector_type(8))) short bf16x8;
typedef __attribute__((ext_vector_type(4))) float f32x4;

__device__ __forceinline__ unsigned short f2bf(float f) {
    unsigned int u = __float_as_uint(f);
    return (unsigned short)((u + 0x7FFFu + ((u >> 16) & 1u)) >> 16);  // RNE
}

// 16-lane butterfly reduction on the VALU via DPP (no LDS-pipe traffic).
__device__ __forceinline__ float red16(float v) {
    int x;
    x = __builtin_amdgcn_update_dpp(0, __float_as_int(v), 0xB1, 0xF, 0xF, true);  // quad_perm xor1
    v += __int_as_float(x);
    x = __builtin_amdgcn_update_dpp(0, __float_as_int(v), 0x4E, 0xF, 0xF, true);  // quad_perm xor2
    v += __int_as_float(x);
    x = __builtin_amdgcn_update_dpp(0, __float_as_int(v), 0x141, 0xF, 0xF, true); // row_half_mirror
    v += __int_as_float(x);
    x = __builtin_amdgcn_update_dpp(0, __float_as_int(v), 0x140, 0xF, 0xF, true); // row_mirror
    v += __int_as_float(x);
    return v;
}

// W2 [256][1024] fp32 -> w2t [col][k] bf16, pre-scaled by log2(e) so the
// epilogue exp is a bare v_exp_f32. k XOR-swizzled within each 64-chunk
// (same scheme as R2 — verified conflict-light + global_load_lds friendly).
__global__ void prep_w2(const float* __restrict__ W2, unsigned short* __restrict__ w2t) {
    const int g = blockIdx.x * 256 + threadIdx.x;   // g = k*1024 + col
    const int col = g & (NCOL - 1), k = g >> 10;
    w2t[col * HID + (k & ~63) + ((k & 63) ^ ((col & 7) << 3))] = f2bf(W2[g] * LOG2E);
}

__global__ __launch_bounds__(256, 2)
void gplc2(const float* __restrict__ x,
           const float* __restrict__ W1,
           const float* __restrict__ b1,
           const unsigned short* __restrict__ w2t,
           const float* __restrict__ b2,
           float* __restrict__ out)
{
    __shared__ float xs[ROWSB * XC];                       // 8704 B, live whole kernel
    __shared__ __align__(16) union {
        unsigned short hb[ROWSB * HID];                    // 65536 B (phase 1 + A-frag load)
        struct { unsigned short w2[2][NB * 64]; float b2s[NCOL]; } g;  // 36864 B (t-loop)
    } u;                                                   // total LDS 74240 B -> 2 blocks/CU

    const int tid  = threadIdx.x;
    const int lane = tid & 63;
    const int w    = tid >> 6;        // wave 0..3 -> rows w*32..w*32+31
    const int quad = lane >> 4;
    const int l15  = lane & 15;
    const int wr   = w * 32;
    const int ksw  = (lane & 7) << 3; // B-frag k swizzle
    const size_t r0 = (size_t)blockIdx.x * ROWSB;

    // stage x tile (coalesced); W1 columns + b1 straight from L2 into regs
    for (int i = tid; i < ROWSB * XC; i += 256) xs[i] = x[r0 * XC + i];
    const int cp = tid & 127, hlf = tid >> 7;
    float w1r[16];
    #pragma unroll
    for (int i = 0; i < 8; ++i) {
        const float2 t2 = *(const float2*)&W1[i * HID + 2 * cp];
        w1r[2 * i] = t2.x; w1r[2 * i + 1] = t2.y;
    }
    const float2 b1v = *(const float2*)&b1[2 * cp];
    __syncthreads();

    // ---- phase 1: h = relu(xA@W1+b1) -> bf16 LDS, granule-XOR-swizzled rows
    for (int r = 0; r < 64; ++r) {
        const int row = hlf * 64 + r;
        float a0 = b1v.x, a1 = b1v.y;
        #pragma unroll
        for (int i = 0; i < 8; ++i) {
            const float xv = xs[row * XC + i];     // broadcast read
            a0 = fmaf(xv, w1r[2 * i], a0);
            a1 = fmaf(xv, w1r[2 * i + 1], a1);
        }
        a0 = fmaxf(a0, 0.f); a1 = fmaxf(a1, 0.f);
        const int gidx = cp >> 2;                  // 8-elem granule
        const int eidx = row * HID + (((gidx) ^ (row & 15)) << 3) + ((cp & 3) << 1);
        *(unsigned int*)&u.hb[eidx] = (unsigned int)f2bf(a0) | ((unsigned int)f2bf(a1) << 16);
    }
    __syncthreads();

    // ---- A-fragment register cache: 32 rows x 256 K per wave, read ONCE
    bf16x8 afr[2][8];
    #pragma unroll
    for (int rt = 0; rt < 2; ++rt)
        #pragma unroll
        for (int kf = 0; kf < 8; ++kf) {
            const int row = wr + rt * 16 + l15;    // row&15 == l15
            afr[rt][kf] = *(const bf16x8*)&u.hb[row * HID + (((kf * 4 + quad) ^ l15) << 3)];
        }
    __syncthreads();   // hb dead; union region becomes w2 dbuf + b2s

    for (int i = tid; i < NCOL; i += 256) u.g.b2s[i] = b2[i] * LOG2E;

    // stage K-chunk n (t = n>>2, kc = n&3): 16 KB linear global_load_lds copy
    auto stage = [&](int n) {
        const int t = n >> 2, kc = n & 3, buf = n & 1;
        #pragma unroll
        for (int j = 0; j < 4; ++j) {
            const int ob = (w * 4 + j) * 512;              // wave-uniform LDS base
            const int c  = (ob >> 6) + (lane >> 3);        // local col 0..127
            const int kl = (lane & 7) << 3;
            const unsigned short* gp = w2t + (size_t)(t * NB + c) * HID + kc * 64 + kl;
            unsigned short* lp = &u.g.w2[buf][ob];
            __builtin_amdgcn_global_load_lds(
                (const __attribute__((address_space(1))) unsigned int*)gp,
                (__attribute__((address_space(3))) unsigned int*)lp, 16, 0, 0);
        }
    };

    f32x4 acc[2][8];
    #pragma unroll
    for (int rt = 0; rt < 2; ++rt)
        #pragma unroll
        for (int ct = 0; ct < 8; ++ct) acc[rt][ct] = (f32x4){0.f, 0.f, 0.f, 0.f};
    float jf[2][4] = {{1.f,1.f,1.f,1.f},{1.f,1.f,1.f,1.f}};

    stage(0);
    #pragma unroll 1
    for (int n = 0; n < 32; ++n) {
        __syncthreads();                   // chunk n staged; prev readers drained
        if (n < 31) stage(n + 1);
        const unsigned short* wsb = u.g.w2[n & 1];
        const int kc = n & 3;
        #pragma unroll
        for (int ks = 0; ks < 2; ++ks) {
            const int kf = kc * 2 + ks;
            const int klog = ks * 32 + quad * 8;
            #pragma unroll
            for (int ct = 0; ct < 8; ++ct) {
                const int c = ct * 16 + l15;
                const bf16x8 bf = *(const bf16x8*)&wsb[c * 64 + (klog ^ ksw)];
                acc[0][ct] = __builtin_amdgcn_mfma_f32_16x16x32_bf16(afr[0][kf], bf, acc[0][ct], 0, 0, 0);
                acc[1][ct] = __builtin_amdgcn_mfma_f32_16x16x32_bf16(afr[1][kf], bf, acc[1][ct], 0, 0, 0);
            }
        }

        if (kc == 3) {                     // transform t complete -> fused epilogue
            const int t = n >> 2;
            float bb[8];
            #pragma unroll
            for (int ct = 0; ct < 8; ++ct) bb[ct] = u.g.b2s[t * NB + ct * 16 + l15];
            #pragma unroll
            for (int rt = 0; rt < 2; ++rt)
                #pragma unroll
                for (int i = 0; i < 4; ++i) {
                    const int row = wr + rt * 16 + quad * 4 + i;
                    const float alpha = xs[row * XC + 8 + t] * 128.f;   // broadcast
                    const float fb = floorf(alpha);
                    const int bin = min(max((int)fb, 0), 127);
                    const float fr = alpha - fb;
                    float tot = 0.f, num = 0.f, eb = 0.f;
                    #pragma unroll
                    for (int ct = 0; ct < 8; ++ct) {
                        const int col = ct * 16 + l15;
                        const float e = exp2f(acc[rt][ct][i] + bb[ct]);  // v_exp_f32
                        tot += e;
                        num += (col < bin)  ? e : 0.f;
                        eb  += (col == bin) ? e : 0.f;
                    }
                    tot = red16(tot); num = red16(num); eb = red16(eb);
                    const float inv = 1.f / tot;
                    jf[rt][i] *= 128.f * eb * inv;
                    if (l15 == 0) xs[row * XC + 8 + t] = fmaf(eb, fr, num) * inv;
                }
            #pragma unroll
            for (int rt = 0; rt < 2; ++rt)
                #pragma unroll
                for (int ct = 0; ct < 8; ++ct) acc[rt][ct] = (f32x4){0.f, 0.f, 0.f, 0.f};
        }
    }

    // jacobian into xs, then one fully-coalesced block copy-out
    if (l15 == 0) {
        #pragma unroll
        for (int rt = 0; rt < 2; ++rt)
            #pragma unroll
            for (int i = 0; i < 4; ++i) {
                const int row = wr + rt * 16 + quad * 4 + i;
                xs[row * XC + 16] *= jf[rt][i];
            }
    }
    __syncthreads();
    for (int i = tid; i < ROWSB * XC; i += 256) out[r0 * XC + i] = xs[i];
}

extern "C" void kernel_launch(void* const* d_in, const int* in_sizes, int n_in,
                              void* d_out, int out_size, void* d_ws, size_t ws_size,
                              hipStream_t stream) {
    (void)in_sizes; (void)n_in; (void)ws_size; (void)out_size;
    prep_w2<<<(HID * NCOL) / 256, 256, 0, stream>>>(
        (const float*)d_in[3], (unsigned short*)d_ws);
    gplc2<<<NROWS / ROWSB, 256, 0, stream>>>(
        (const float*)d_in[0], (const float*)d_in[1], (const float*)d_in[2],
        (const unsigned short*)d_ws, (const float*)d_in[4], (float*)d_out);
}